// Round 1
// baseline (892.155 us; speedup 1.0000x reference)
//
#include <hip/hip_runtime.h>
#include <math.h>

// Problem constants (S=3, Q=64, X=128, Y=128, Z=32, C=21)
#define NVOX 524288          // X*Y*Z
#define WPR  8192            // NVOX/64 bitmask words per query row
#define QN   64              // queries
#define SN   3               // subnets
#define CN   21              // classes

__device__ __forceinline__ float sigmoidf_(float x) {
    return 1.0f / (1.0f + expf(-x));
}

// ---------------------------------------------------------------------------
// K1: pack (logit > 0) bits for all S*Q rows into uint64 words via __ballot.
// Grid: (SN*QN*WPR)/16 blocks of 256 (4 waves x 4 words each).
// ---------------------------------------------------------------------------
__global__ __launch_bounds__(256) void mask_kernel(
    const float* __restrict__ logits, unsigned long long* __restrict__ B) {
    int tid = threadIdx.x;
    int wave = tid >> 6, lane = tid & 63;
    int wbase = (blockIdx.x * 4 + wave) * 4;   // aligned group of 4 words
#pragma unroll
    for (int k = 0; k < 4; ++k) {
        int wi = wbase + k;
        int r = wi >> 13;          // row in [0, SN*QN)
        int w = wi & (WPR - 1);
        float x = logits[r * NVOX + (w << 6) + lane];
        unsigned long long m = __ballot(x > 0.0f);
        if (lane == 0) B[wi] = m;
    }
}

// ---------------------------------------------------------------------------
// K2: per-row popcount sums. Grid: nrows blocks of 256.
// ---------------------------------------------------------------------------
__global__ __launch_bounds__(256) void rowsum_kernel(
    const unsigned long long* __restrict__ B, unsigned int* __restrict__ cnt) {
    int r = blockIdx.x, tid = threadIdx.x;
    const unsigned long long* row = B + r * WPR;
    int s = 0;
    for (int w = tid; w < WPR; w += 256) s += __popcll(row[w]);
    for (int off = 32; off; off >>= 1) s += __shfl_down(s, off);
    __shared__ int red[4];
    if ((tid & 63) == 0) red[tid >> 6] = s;
    __syncthreads();
    if (tid == 0) cnt[r] = (unsigned)(red[0] + red[1] + red[2] + red[3]);
}

// ---------------------------------------------------------------------------
// K3: inter[q][p] = popcount(Ba[q] & Bb[p]). 4x4 output tile per block.
// Grid: (16,16) blocks of 256.
// ---------------------------------------------------------------------------
__global__ __launch_bounds__(256) void inter_kernel(
    const unsigned long long* __restrict__ Ba,
    const unsigned long long* __restrict__ Bb,
    unsigned int* __restrict__ inter) {
    int q0 = blockIdx.y * 4, p0 = blockIdx.x * 4;
    int tid = threadIdx.x;
    int acc[4][4] = {};
    for (int w = tid; w < WPR; w += 256) {
        unsigned long long a[4], b[4];
#pragma unroll
        for (int i = 0; i < 4; ++i) a[i] = Ba[(q0 + i) * WPR + w];
#pragma unroll
        for (int j = 0; j < 4; ++j) b[j] = Bb[(p0 + j) * WPR + w];
#pragma unroll
        for (int i = 0; i < 4; ++i)
#pragma unroll
            for (int j = 0; j < 4; ++j) acc[i][j] += __popcll(a[i] & b[j]);
    }
    __shared__ int red[16][4];
    int lane = tid & 63, wave = tid >> 6;
#pragma unroll
    for (int i = 0; i < 4; ++i)
#pragma unroll
        for (int j = 0; j < 4; ++j) {
            int v = acc[i][j];
            for (int off = 32; off; off >>= 1) v += __shfl_down(v, off);
            if (lane == 0) red[i * 4 + j][wave] = v;
        }
    __syncthreads();
    if (tid < 16) {
        int s = red[tid][0] + red[tid][1] + red[tid][2] + red[tid][3];
        inter[(q0 + (tid >> 2)) * QN + (p0 + (tid & 3))] = (unsigned)s;
    }
}

// ---------------------------------------------------------------------------
// K4: per-anchor argmax IoU (first-max semantics to match np.argmax),
// matched flag, and (stage 2) keep = mean(iou) > 0.2.
// Grid: 1 block of 64.
// ---------------------------------------------------------------------------
__global__ void finalize_kernel(
    const unsigned int* __restrict__ inter,
    const unsigned int* __restrict__ cnt_a,
    const unsigned int* __restrict__ cnt_b,
    int* __restrict__ idx, int* __restrict__ matched,
    float* __restrict__ iou_out,
    int stage2, const float* __restrict__ iou_prev, float* __restrict__ keep) {
    int q = threadIdx.x;
    if (q >= QN) return;
    float na = (float)cnt_a[q];
    float best = -1.0f;
    int bidx = 0;
    for (int p = 0; p < QN; ++p) {
        float fi = (float)inter[q * QN + p];
        float un = fmaxf(na + (float)cnt_b[p] - fi, 1.0f);
        float iou = fi / un;               // exact fp32 div of exact ints == ref
        if (iou > best) { best = iou; bidx = p; }   // strict > keeps first max
    }
    idx[q] = bidx;
    iou_out[q] = best;
    matched[q] = (best > 0.2f) ? 1 : 0;
    if (stage2) keep[q] = (((iou_prev[q] + best) * 0.5f) > 0.2f) ? 1.0f : 0.0f;
}

// ---------------------------------------------------------------------------
// K5: iteration-2 anchor mask: matched ? (s0 + s1[idx]) > 1 : (x0 > 0).
// Grid: (QN*WPR)/16 blocks of 256.
// ---------------------------------------------------------------------------
__global__ __launch_bounds__(256) void mask2_kernel(
    const float* __restrict__ logits,
    const int* __restrict__ idx1, const int* __restrict__ m1,
    unsigned long long* __restrict__ B0p) {
    int tid = threadIdx.x;
    int wave = tid >> 6, lane = tid & 63;
    int wbase = (blockIdx.x * 4 + wave) * 4;   // 4 aligned words, same row
    int q = wbase >> 13;
    int m = m1[q], j = idx1[q];
    const float* L0 = logits;
    const float* L1 = logits + QN * NVOX;
#pragma unroll
    for (int k = 0; k < 4; ++k) {
        int wi = wbase + k;
        int w = wi & (WPR - 1);
        int n = (w << 6) + lane;
        float x0 = L0[q * NVOX + n];
        bool pred;
        if (m) {
            float s0 = sigmoidf_(x0);
            float s1 = sigmoidf_(L1[j * NVOX + n]);
            pred = (s0 + s1) > 1.0f;       // == ((s0+s1)/2 > 0.5), halving exact
        } else {
            pred = x0 > 0.0f;
        }
        unsigned long long mk = __ballot(pred);
        if (lane == 0) B0p[wi] = mk;
    }
}

// ---------------------------------------------------------------------------
// K6: final output. One thread per voxel column n, loop over q (coalesced).
// out[q,n] = merged_anchor(q,n) * keep[q] * occ(n). Grid: NVOX/256 blocks.
// ---------------------------------------------------------------------------
__global__ __launch_bounds__(256) void final_kernel(
    const float* __restrict__ logits,
    const float* __restrict__ sem,
    const int* __restrict__ idx1_, const int* __restrict__ m1_,
    const int* __restrict__ idx2_, const int* __restrict__ m2_,
    const float* __restrict__ keep_,
    float* __restrict__ out) {
    __shared__ int sidx1[QN], sm1[QN], sidx2[QN], sm2[QN];
    __shared__ float skeep[QN];
    int tid = threadIdx.x;
    if (tid < QN) {
        sidx1[tid] = idx1_[tid]; sm1[tid] = m1_[tid];
        sidx2[tid] = idx2_[tid]; sm2[tid] = m2_[tid];
        skeep[tid] = keep_[tid];
    }
    __syncthreads();
    int n = blockIdx.x * 256 + tid;
    // occ = (argmax_c sem[c,n] != 0) == (max_{c>=1} > sem[0])  (tie -> class 0)
    float s0c = sem[n];
    float mx = sem[NVOX + n];
#pragma unroll
    for (int c = 2; c < CN; ++c) mx = fmaxf(mx, sem[c * NVOX + n]);
    float occ = (mx > s0c) ? 1.0f : 0.0f;
    const float* L0 = logits;
    const float* L1 = logits + QN * NVOX;
    const float* L2 = logits + 2 * QN * NVOX;
    for (int q = 0; q < QN; ++q) {
        float a = sigmoidf_(L0[q * NVOX + n]);
        if (sm1[q]) {
            float s1 = sigmoidf_(L1[sidx1[q] * NVOX + n]);
            a = (a + s1) * 0.5f;            // == /2, exact
        }
        if (sm2[q]) {
            float s2 = sigmoidf_(L2[sidx2[q] * NVOX + n]);
            a = (a * 2.0f + s2) / 3.0f;     // IEEE div to match reference
        }
        out[q * NVOX + n] = a * skeep[q] * occ;
    }
}

// ---------------------------------------------------------------------------
extern "C" void kernel_launch(void* const* d_in, const int* in_sizes, int n_in,
                              void* d_out, int out_size, void* d_ws, size_t ws_size,
                              hipStream_t stream) {
    const float* vox = (const float*)d_in[0];   // [3, 64, 524288]
    const float* sem = (const float*)d_in[2];   // [21, 524288]
    float* out = (float*)d_out;                 // [64, 524288]

    // Workspace layout (~16.1 MB)
    char* p = (char*)d_ws;
    unsigned long long* Ball = (unsigned long long*)p;   // B0,B1,B2,B0p: 4*4MB
    unsigned long long* B0  = Ball;
    unsigned long long* B1  = Ball + 1 * QN * WPR;
    unsigned long long* B2  = Ball + 2 * QN * WPR;
    unsigned long long* B0p = Ball + 3 * QN * WPR;
    unsigned int* inter1 = (unsigned int*)(p + 16u * 1024u * 1024u);
    unsigned int* inter2 = inter1 + QN * QN;
    unsigned int* cnt    = inter2 + QN * QN;    // [256]: rows0-191 then B0p rows
    int*   idx1 = (int*)(cnt + 256);
    int*   idx2 = idx1 + QN;
    int*   m1   = idx2 + QN;
    int*   m2   = m1 + QN;
    float* iou1 = (float*)(m2 + QN);
    float* iou2 = iou1 + QN;
    float* keep = iou2 + QN;
    (void)in_sizes; (void)n_in; (void)out_size; (void)ws_size;

    // Stage 0: bitmasks for all 3 subnets
    mask_kernel<<<(SN * QN * WPR) / 16, 256, 0, stream>>>(vox, Ball);
    rowsum_kernel<<<SN * QN, 256, 0, stream>>>(Ball, cnt);

    // Stage 1 matching: anchor(B0) vs aux1(B1)
    inter_kernel<<<dim3(16, 16), 256, 0, stream>>>(B0, B1, inter1);
    finalize_kernel<<<1, 64, 0, stream>>>(inter1, cnt, cnt + QN, idx1, m1, iou1,
                                          0, nullptr, nullptr);

    // Stage 2 matching: merged anchor mask vs aux2(B2)
    mask2_kernel<<<(QN * WPR) / 16, 256, 0, stream>>>(vox, idx1, m1, B0p);
    rowsum_kernel<<<QN, 256, 0, stream>>>(B0p, cnt + 3 * QN);
    inter_kernel<<<dim3(16, 16), 256, 0, stream>>>(B0p, B2, inter2);
    finalize_kernel<<<1, 64, 0, stream>>>(inter2, cnt + 3 * QN, cnt + 2 * QN,
                                          idx2, m2, iou2, 1, iou1, keep);

    // Final output
    final_kernel<<<NVOX / 256, 256, 0, stream>>>(vox, sem, idx1, m1, idx2, m2,
                                                 keep, out);
}

// Round 2
// 745.540 us; speedup vs baseline: 1.1967x; 1.1967x over previous
//
#include <hip/hip_runtime.h>

// Problem constants (S=3, Q=64, X=128, Y=128, Z=32, C=21)
#define NVOX 524288          // X*Y*Z voxels
#define NV4  131072          // NVOX/4 float4s per row
#define WPR  8192            // NVOX/64 bitmask words per query row
#define QN   64
#define SN   3
#define CN   21

typedef unsigned long long u64;

// Fast sigmoid for OUTPUT VALUES only (decisions are exact-integer popcounts).
// __expf + v_rcp: ~1e-7 rel err vs 1.9e-2 threshold.
__device__ __forceinline__ float fast_sigmoid(float x) {
    return __builtin_amdgcn_rcpf(1.0f + __expf(-x));
}

// ---------------------------------------------------------------------------
// K1: fused mask-build + row popcount for all S*Q rows. float4 loads.
// Bit mapping (permuted, consistent across ALL mask producers):
//   wave handles 64 consecutive float4 = 256 voxels = segment seg;
//   lane L holds voxels 4L..4L+3 as nibble bits j=0..3;
//   word seg*4+j = ballot(nibble bit j).
// Grid: 192 rows x 8 chunks = 1536 blocks of 256.
// ---------------------------------------------------------------------------
__global__ __launch_bounds__(256) void mask_rowsum_kernel(
    const float4* __restrict__ logits4, u64* __restrict__ B,
    unsigned int* __restrict__ part) {
    int r = blockIdx.x >> 3, c = blockIdx.x & 7;
    int tid = threadIdx.x, lane = tid & 63, wave = tid >> 6;
    const float4* row = logits4 + (size_t)r * NV4;
    int base = c * (NV4 / 8);          // 16384 float4 per chunk
    int pcnt = 0;
#pragma unroll 2
    for (int it = 0; it < 64; ++it) {
        int idx = base + it * 256 + tid;            // float4 index
        float4 v = row[idx];
        int nib = (v.x > 0.f ? 1 : 0) | (v.y > 0.f ? 2 : 0) |
                  (v.z > 0.f ? 4 : 0) | (v.w > 0.f ? 8 : 0);
        pcnt += __popc(nib);
        u64 b0 = __ballot(nib & 1);
        u64 b1 = __ballot(nib & 2);
        u64 b2 = __ballot(nib & 4);
        u64 b3 = __ballot(nib & 8);
        if (lane == 0) {
            int seg = idx >> 6;                     // wave-uniform
            ulonglong2* dst = (ulonglong2*)&B[(size_t)r * WPR + (size_t)seg * 4];
            dst[0] = make_ulonglong2(b0, b1);
            dst[1] = make_ulonglong2(b2, b3);
        }
    }
    for (int off = 32; off; off >>= 1) pcnt += __shfl_down(pcnt, off);
    __shared__ int red[4];
    if (lane == 0) red[wave] = pcnt;
    __syncthreads();
    if (tid == 0) part[blockIdx.x] = (unsigned)(red[0] + red[1] + red[2] + red[3]);
}

// ---------------------------------------------------------------------------
// K2: occupancy per voxel: occ = (max_{c>=1} sem[c] > sem[0]). float4.
// Grid: NV4/256 = 512 blocks.
// ---------------------------------------------------------------------------
__global__ __launch_bounds__(256) void occ_kernel(
    const float4* __restrict__ sem4, float4* __restrict__ occ4) {
    int n4 = blockIdx.x * 256 + threadIdx.x;
    float4 s0 = sem4[n4];
    float4 mx = sem4[NV4 + n4];
#pragma unroll
    for (int c = 2; c < CN; ++c) {
        float4 s = sem4[(size_t)c * NV4 + n4];
        mx.x = fmaxf(mx.x, s.x); mx.y = fmaxf(mx.y, s.y);
        mx.z = fmaxf(mx.z, s.z); mx.w = fmaxf(mx.w, s.w);
    }
    float4 o;
    o.x = (mx.x > s0.x) ? 1.f : 0.f; o.y = (mx.y > s0.y) ? 1.f : 0.f;
    o.z = (mx.z > s0.z) ? 1.f : 0.f; o.w = (mx.w > s0.w) ? 1.f : 0.f;
    occ4[n4] = o;
}

// ---------------------------------------------------------------------------
// K3: inter[q][p] = popcount(Ba[q] & Bb[p]), 4x4 tile/block, ulonglong2 loads.
// Grid: (16,16) blocks of 256.
// ---------------------------------------------------------------------------
__global__ __launch_bounds__(256) void inter_kernel(
    const u64* __restrict__ Ba, const u64* __restrict__ Bb,
    unsigned int* __restrict__ inter) {
    int q0 = blockIdx.y * 4, p0 = blockIdx.x * 4;
    int tid = threadIdx.x;
    const ulonglong2* A2 = (const ulonglong2*)Ba;
    const ulonglong2* B2 = (const ulonglong2*)Bb;
    int acc[4][4] = {};
    for (int w = tid; w < WPR / 2; w += 256) {
        ulonglong2 a[4], b[4];
#pragma unroll
        for (int i = 0; i < 4; ++i) a[i] = A2[(size_t)(q0 + i) * (WPR / 2) + w];
#pragma unroll
        for (int j = 0; j < 4; ++j) b[j] = B2[(size_t)(p0 + j) * (WPR / 2) + w];
#pragma unroll
        for (int i = 0; i < 4; ++i)
#pragma unroll
            for (int j = 0; j < 4; ++j)
                acc[i][j] += __popcll(a[i].x & b[j].x) + __popcll(a[i].y & b[j].y);
    }
    __shared__ int red[16][4];
    int lane = tid & 63, wave = tid >> 6;
#pragma unroll
    for (int i = 0; i < 4; ++i)
#pragma unroll
        for (int j = 0; j < 4; ++j) {
            int v = acc[i][j];
            for (int off = 32; off; off >>= 1) v += __shfl_down(v, off);
            if (lane == 0) red[i * 4 + j][wave] = v;
        }
    __syncthreads();
    if (tid < 16) {
        int s = red[tid][0] + red[tid][1] + red[tid][2] + red[tid][3];
        inter[(q0 + (tid >> 2)) * QN + (p0 + (tid & 3))] = (unsigned)s;
    }
}

// ---------------------------------------------------------------------------
// K4: per-anchor first-max argmax IoU + matched; stage2 also keep.
// pa: partial counts (8/row) for anchor rows; pa_alt/sel: stage2 fallback to
// original B0 counts for unmatched rows. Grid: 1 block of 64.
// ---------------------------------------------------------------------------
__global__ void finalize_kernel(
    const unsigned int* __restrict__ inter,
    const unsigned int* __restrict__ pa,
    const unsigned int* __restrict__ pa_alt, const int* __restrict__ sel,
    const unsigned int* __restrict__ pb,
    int* __restrict__ idx, int* __restrict__ matched, float* __restrict__ iou_out,
    int stage2, const float* __restrict__ iou_prev, float* __restrict__ keep) {
    __shared__ float nb[QN];
    int q = threadIdx.x;
    unsigned sb = 0;
#pragma unroll
    for (int k = 0; k < 8; ++k) sb += pb[q * 8 + k];
    nb[q] = (float)sb;
    __syncthreads();
    const unsigned int* pr = (sel && !sel[q]) ? pa_alt : pa;
    unsigned sa = 0;
#pragma unroll
    for (int k = 0; k < 8; ++k) sa += pr[q * 8 + k];
    float na = (float)sa;
    float best = -1.0f;
    int bidx = 0;
    for (int p = 0; p < QN; ++p) {
        float fi = (float)inter[q * QN + p];
        float un = fmaxf(na + nb[p] - fi, 1.0f);
        float iou = fi / un;                 // exact ints -> deterministic
        if (iou > best) { best = iou; bidx = p; }   // strict > = first max
    }
    idx[q] = bidx;
    iou_out[q] = best;
    matched[q] = (best > 0.2f) ? 1 : 0;
    if (stage2) keep[q] = (((iou_prev[q] + best) * 0.5f) > 0.2f) ? 1.0f : 0.0f;
}

// ---------------------------------------------------------------------------
// K5: merged anchor mask, IN PLACE over B0 (B0p aliases B0).
// matched: bit = (x0 + x1[idx]) > 0   [== (s0+s1)/2 > 0.5, sigmoid monotone]
// unmatched: B0 row already holds the correct bits -> early exit, no traffic.
// Grid: 64 rows x 8 chunks = 512 blocks of 256.
// ---------------------------------------------------------------------------
__global__ __launch_bounds__(256) void mask2_kernel(
    const float4* __restrict__ logits4,
    const int* __restrict__ idx1, const int* __restrict__ m1,
    u64* __restrict__ B0p, unsigned int* __restrict__ partP) {
    int q = blockIdx.x >> 3, c = blockIdx.x & 7;
    if (!m1[q]) return;                       // row keeps B0 bits + counts
    int tid = threadIdx.x, lane = tid & 63, wave = tid >> 6;
    const float4* r0 = logits4 + (size_t)q * NV4;
    const float4* r1 = logits4 + (size_t)(QN + idx1[q]) * NV4;
    int base = c * (NV4 / 8);
    int pcnt = 0;
#pragma unroll 2
    for (int it = 0; it < 64; ++it) {
        int idx = base + it * 256 + tid;
        float4 a = r0[idx];
        float4 b = r1[idx];
        int nib = (a.x + b.x > 0.f ? 1 : 0) | (a.y + b.y > 0.f ? 2 : 0) |
                  (a.z + b.z > 0.f ? 4 : 0) | (a.w + b.w > 0.f ? 8 : 0);
        pcnt += __popc(nib);
        u64 b0 = __ballot(nib & 1);
        u64 b1 = __ballot(nib & 2);
        u64 b2 = __ballot(nib & 4);
        u64 b3 = __ballot(nib & 8);
        if (lane == 0) {
            int seg = idx >> 6;
            ulonglong2* dst = (ulonglong2*)&B0p[(size_t)q * WPR + (size_t)seg * 4];
            dst[0] = make_ulonglong2(b0, b1);
            dst[1] = make_ulonglong2(b2, b3);
        }
    }
    for (int off = 32; off; off >>= 1) pcnt += __shfl_down(pcnt, off);
    __shared__ int red[4];
    if (lane == 0) red[wave] = pcnt;
    __syncthreads();
    if (tid == 0) partP[blockIdx.x] = (unsigned)(red[0] + red[1] + red[2] + red[3]);
}

// ---------------------------------------------------------------------------
// K6: final output, float4, branchless (unconditional gathers + selects),
// q-loop split across grid.y for occupancy. Grid: (512, 2) blocks of 256.
// ---------------------------------------------------------------------------
__global__ __launch_bounds__(256) void final_kernel(
    const float4* __restrict__ logits4, const float4* __restrict__ occ4,
    const int* __restrict__ idx1_, const int* __restrict__ m1_,
    const int* __restrict__ idx2_, const int* __restrict__ m2_,
    const float* __restrict__ keep_, float4* __restrict__ out4) {
    __shared__ int sj1[32], sm1[32], sj2[32], sm2[32];
    __shared__ float sk[32];
    int tid = threadIdx.x;
    int qbase = blockIdx.y * 32;
    if (tid < 32) {
        sj1[tid] = idx1_[qbase + tid]; sm1[tid] = m1_[qbase + tid];
        sj2[tid] = idx2_[qbase + tid]; sm2[tid] = m2_[qbase + tid];
        sk[tid] = keep_[qbase + tid];
    }
    __syncthreads();
    int n4 = blockIdx.x * 256 + tid;
    float4 oc = occ4[n4];
#pragma unroll 2
    for (int qq = 0; qq < 32; ++qq) {
        int q = qbase + qq;
        bool m1 = sm1[qq] != 0, m2 = sm2[qq] != 0;
        float4 l0 = logits4[(size_t)q * NV4 + n4];
        float4 l1 = logits4[(size_t)(QN + sj1[qq]) * NV4 + n4];
        float4 l2 = logits4[(size_t)(2 * QN + sj2[qq]) * NV4 + n4];
        float a0 = fast_sigmoid(l0.x), a1 = fast_sigmoid(l0.y);
        float a2 = fast_sigmoid(l0.z), a3 = fast_sigmoid(l0.w);
        if (m1) {
            a0 = (a0 + fast_sigmoid(l1.x)) * 0.5f;
            a1 = (a1 + fast_sigmoid(l1.y)) * 0.5f;
            a2 = (a2 + fast_sigmoid(l1.z)) * 0.5f;
            a3 = (a3 + fast_sigmoid(l1.w)) * 0.5f;
        }
        if (m2) {
            const float t = 1.0f / 3.0f;
            a0 = (a0 * 2.f + fast_sigmoid(l2.x)) * t;
            a1 = (a1 * 2.f + fast_sigmoid(l2.y)) * t;
            a2 = (a2 * 2.f + fast_sigmoid(l2.z)) * t;
            a3 = (a3 * 2.f + fast_sigmoid(l2.w)) * t;
        }
        float kq = sk[qq];
        float4 o;
        o.x = a0 * kq * oc.x; o.y = a1 * kq * oc.y;
        o.z = a2 * kq * oc.z; o.w = a3 * kq * oc.w;
        out4[(size_t)q * NV4 + n4] = o;
    }
}

// ---------------------------------------------------------------------------
extern "C" void kernel_launch(void* const* d_in, const int* in_sizes, int n_in,
                              void* d_out, int out_size, void* d_ws, size_t ws_size,
                              hipStream_t stream) {
    const float4* vox4 = (const float4*)d_in[0];   // [3*64, 131072] float4
    const float4* sem4 = (const float4*)d_in[2];   // [21, 131072] float4
    float4* out4 = (float4*)d_out;
    (void)in_sizes; (void)n_in; (void)out_size; (void)ws_size; (void)d_in;

    // Workspace (~14.1 MB)
    char* p = (char*)d_ws;
    u64* Ball = (u64*)p;                            // 3 rowsets x 4 MB
    u64* B0 = Ball;                                 // B0p aliases B0 (in-place)
    u64* B1 = Ball + 1 * (size_t)QN * WPR;
    u64* B2 = Ball + 2 * (size_t)QN * WPR;
    char* p2 = p + 3ull * QN * WPR * 8;             // 12 MB
    float4* occ4 = (float4*)p2;                     // 2 MB
    char* p3 = p2 + (size_t)NVOX * 4;
    unsigned int* inter1 = (unsigned int*)p3;       // 4096
    unsigned int* inter2 = inter1 + QN * QN;
    unsigned int* partA  = inter2 + QN * QN;        // 192*8
    unsigned int* partP  = partA + 192 * 8;         // 64*8
    int* idx1 = (int*)(partP + 64 * 8);
    int* idx2 = idx1 + QN;
    int* m1   = idx2 + QN;
    int* m2   = m1 + QN;
    float* iou1 = (float*)(m2 + QN);
    float* iou2 = iou1 + QN;
    float* keep = iou2 + QN;

    // Stage 0: masks + row counts for all 3 subnets; occ map
    mask_rowsum_kernel<<<SN * QN * 8, 256, 0, stream>>>(vox4, Ball, partA);
    occ_kernel<<<NV4 / 256, 256, 0, stream>>>(sem4, occ4);

    // Stage 1 matching: B0 vs B1
    inter_kernel<<<dim3(16, 16), 256, 0, stream>>>(B0, B1, inter1);
    finalize_kernel<<<1, 64, 0, stream>>>(inter1, partA, nullptr, nullptr,
                                          partA + QN * 8, idx1, m1, iou1,
                                          0, nullptr, nullptr);

    // Stage 2: merged anchor mask (in place over B0), then vs B2
    mask2_kernel<<<QN * 8, 256, 0, stream>>>(vox4, idx1, m1, B0, partP);
    inter_kernel<<<dim3(16, 16), 256, 0, stream>>>(B0, B2, inter2);
    finalize_kernel<<<1, 64, 0, stream>>>(inter2, partP, partA, m1,
                                          partA + 2 * QN * 8, idx2, m2, iou2,
                                          1, iou1, keep);

    // Final output
    final_kernel<<<dim3(NV4 / 256, 2), 256, 0, stream>>>(
        vox4, occ4, idx1, m1, idx2, m2, keep, out4);
}